// Round 1
// 65.482 us; speedup vs baseline: 1.0041x; 1.0041x over previous
//
#include <hip/hip_runtime.h>

#define N_POINTS 204800
#define N_GT 256
#define BLOCK 512            // 8 waves
#define GRID 512             // exactly 2 blocks per CU — balanced AND overlapped
#define PTS_PER_BLOCK 400    // 204800 / 512

typedef float v2f __attribute__((ext_vector_type(2)));

__device__ __forceinline__ v2f pk_fma(v2f a, v2f b, v2f c) {
  return __builtin_elementwise_fma(a, b, c);
}
__device__ __forceinline__ v2f lohalf(float4 q) { return (v2f){q.x, q.y}; }
__device__ __forceinline__ v2f hihalf(float4 q) { return (v2f){q.z, q.w}; }

// Math (R1-R8): per box, centerness^2 = max(fx,0)*fy under a >=0 max-reduce
// (one-clamp), fx/fy quadratics in px/py (div folded into coefs), sqrt
// hoisted out of the 256-box max. Coef 24B/box x/y-interleaved.
//
// R9: 256x1024, loop inverted (wave owns 16 boxes, sweeps 800 pts), per-wave
// partials + 16-way LDS reduce. Bench 65.7us (kernel est ~5us; the visible
// 40us top dispatches are harness fillBuffer poisons — not ours).
//
// R10: same VALU total (1008 instrs/wave, 89% slot eff), but 512 blocks x
// 512 threads = exactly 2 resident blocks/CU so the serialized prologue
// (HBM point-load latency + gt staging + barrier) and epilogue (partial
// dump + reduce) of one block overlap the other block's main loop:
//  - wave owns 32 boxes (8 groups of 4), sweeps 400 pts as 7 float2/lane.
//  - LDS 57.3KB -> 18.9KB/block; barriers 16-wave -> 8-wave.
//  - L1 point-read redundancy halves (8 waves/point-set instead of 16).
__global__ __launch_bounds__(BLOCK, 4) void centerness_kernel(
    const float* __restrict__ points, const float* __restrict__ gt,
    float* __restrict__ out) {
  __shared__ float scoef[6 * N_GT];              // 6144 B
  __shared__ float spart[8 * PTS_PER_BLOCK];     // 12800 B (total 18944 B)

  const int t = threadIdx.x;
  const int lane = t & 63;
  const int w = t >> 6;  // wave id = 32-box chunk id

  // Issue the gt load FIRST so coef staging can retire before the point
  // loads drain (vmcnt is counted: staging waits only on this load).
  float4 bb;
  if (t < N_GT) bb = ((const float4*)gt)[t];  // x1,y1,x2,y2

  // --- load this block's 400 points: 7 float2/lane (last one partial) ---
  const int pbase = blockIdx.x * PTS_PER_BLOCK;  // float2 index == point index
  const float2* p2 = (const float2*)points;
  v2f pt[7];
#pragma unroll
  for (int it = 0; it < 6; ++it) {
    float2 v = p2[pbase + it * 64 + lane];
    pt[it] = (v2f){v.x, v.y};
  }
  {
    int idx = pbase + 384 + lane;            // valid only for lane<16
    if (idx > N_POINTS - 1) idx = N_POINTS - 1;  // clamp: garbage write-guarded
    float2 v = p2[idx];
    pt[6] = (v2f){v.x, v.y};
  }

  // --- stage coefficients (threads 0..255, one box each) ---
  if (t < N_GT) {
    float iw = 1.0f / (bb.z - bb.x);
    float ih = 1.0f / (bb.w - bb.y);
    float* c = &scoef[6 * t];
    c[0] = -iw;                 c[1] = -ih;
    c[2] = (bb.x + bb.z) * iw;  c[3] = (bb.y + bb.w) * ih;
    c[4] = -(bb.x * bb.z) * iw; c[5] = -(bb.y * bb.w) * ih;
  }
  __syncthreads();

  float acc[7];
#pragma unroll
  for (int k = 0; k < 7; ++k) acc[k] = 0.f;

  const float4* cw = (const float4*)scoef + w * 48;  // 32 boxes * 6 f / 4

#pragma unroll 1
  for (int g = 0; g < 8; ++g) {
    // 4 boxes = 6 uniform (broadcast) b128 reads, held for the point sweep.
    float4 q0 = cw[6 * g + 0];
    float4 q1 = cw[6 * g + 1];
    float4 q2 = cw[6 * g + 2];
    float4 q3 = cw[6 * g + 3];
    float4 q4 = cw[6 * g + 4];
    float4 q5 = cw[6 * g + 5];
    // box0: a2=lo(q0) a1=hi(q0) a0=lo(q1); box1: a2=hi(q1) a1=lo(q2) a0=hi(q2)
    // box2: a2=lo(q3) a1=hi(q3) a0=lo(q4); box3: a2=hi(q4) a1=lo(q5) a0=hi(q5)
    v2f c0a = lohalf(q0), c0b = hihalf(q0), c0c = lohalf(q1);
    v2f c1a = hihalf(q1), c1b = lohalf(q2), c1c = hihalf(q2);
    v2f c2a = lohalf(q3), c2b = hihalf(q3), c2c = lohalf(q4);
    v2f c3a = hihalf(q4), c3b = lohalf(q5), c3c = hihalf(q5);

#pragma unroll
    for (int it = 0; it < 7; ++it) {
      v2f P = pt[it];  // (px, py) of point it*64+lane
      v2f r0 = pk_fma(pk_fma(c0a, P, c0b), P, c0c);
      v2f r1 = pk_fma(pk_fma(c1a, P, c1b), P, c1c);
      float v0 = fmaxf(r0.x, 0.f) * r0.y;
      float v1 = fmaxf(r1.x, 0.f) * r1.y;
      acc[it] = fmaxf(fmaxf(acc[it], v0), v1);  // v_max3
      v2f r2 = pk_fma(pk_fma(c2a, P, c2b), P, c2c);
      v2f r3 = pk_fma(pk_fma(c3a, P, c3b), P, c3c);
      float v2 = fmaxf(r2.x, 0.f) * r2.y;
      float v3 = fmaxf(r3.x, 0.f) * r3.y;
      acc[it] = fmaxf(fmaxf(acc[it], v2), v3);
    }
  }

  // --- dump per-wave partials: spart[w][pid], pid = it*64 + lane ---
  // bank = (w*400 + it*64 + lane) % 32 = (w*16 + lane) % 32: conflict-free.
#pragma unroll
  for (int it = 0; it < 6; ++it)
    spart[w * PTS_PER_BLOCK + it * 64 + lane] = acc[it];
  if (lane < 16)  // it=6: only 16 valid points (384..399)
    spart[w * PTS_PER_BLOCK + 384 + lane] = acc[6];
  __syncthreads();

  // --- 8-way max reduce: thread t owns point t (t < 400) ---
  // stride 400 floats: bank offset alternates by 16 per row, lanes
  // consecutive -> conflict-free.
  if (t < PTS_PER_BLOCK) {
    float m = spart[t];
#pragma unroll
    for (int i = 1; i < 8; ++i) m = fmaxf(m, spart[i * PTS_PER_BLOCK + t]);
    out[blockIdx.x * PTS_PER_BLOCK + t] = sqrtf(m);
  }
}

extern "C" void kernel_launch(void* const* d_in, const int* in_sizes, int n_in,
                              void* d_out, int out_size, void* d_ws, size_t ws_size,
                              hipStream_t stream) {
  const float* points = (const float*)d_in[0];     // (204800, 2)
  const float* gt_bboxes = (const float*)d_in[1];  // (256, 4)
  // d_in[2] strides: unused by the reference output.
  float* out = (float*)d_out;                      // (204800,)

  centerness_kernel<<<GRID, BLOCK, 0, stream>>>(points, gt_bboxes, out);
}